// Round 13
// baseline (262.787 us; speedup 1.0000x reference)
//
#include <hip/hip_runtime.h>

typedef unsigned short u16;
typedef __bf16 bf16x8 __attribute__((ext_vector_type(8)));
typedef float f32x4 __attribute__((ext_vector_type(4)));

__device__ __forceinline__ float bf2f(u16 u) {
  return __builtin_bit_cast(float, (unsigned)u << 16);
}
__device__ __forceinline__ u16 f2bf(float f) {
  unsigned u = __builtin_bit_cast(unsigned, f);
  u += 0x7FFFu + ((u >> 16) & 1u);  // RNE
  return (u16)(u >> 16);
}
__device__ __forceinline__ unsigned pk2(float a, float b) {
  return (unsigned)f2bf(a) | ((unsigned)f2bf(b) << 16);
}
// truncating pack: [b.hi16 | a.hi16] in ONE v_perm_b32 (bias cancels in P/l)
__device__ __forceinline__ unsigned pk2t(float a, float b) {
  return __builtin_amdgcn_perm(__builtin_bit_cast(unsigned, b),
                               __builtin_bit_cast(unsigned, a), 0x07060302u);
}
__device__ __forceinline__ f32x4 mfma16(bf16x8 a, bf16x8 b, f32x4 c) {
  return __builtin_amdgcn_mfma_f32_16x16x32_bf16(a, b, c, 0, 0, 0);
}
// async 16B/lane global->LDS; LDS dest = wave-uniform base + lane*16
__device__ __forceinline__ void async_cp16(const u16* g, u16* l) {
  __builtin_amdgcn_global_load_lds((const __attribute__((address_space(1))) void*)g,
                                   (__attribute__((address_space(3))) void*)l, 16, 0, 0);
}
#define S_BARRIER() asm volatile("s_barrier" ::: "memory")

// ---------------------------------------------------------------------------
// Fused preprocessing, grid (16,16,16):
//   z 0..6  : weight transposes [R][1024] f32 -> [1024][R] bf16
//   z 7..14 : cast x f32 -> bf16 (2M elements)
//   z 15    : bias concat (first 12 blocks)
// ---------------------------------------------------------------------------
#define TSP 72
__global__ __launch_bounds__(256) void prep_fused(
    const float* __restrict__ We, const float* __restrict__ Wq,
    const float* __restrict__ Wk, const float* __restrict__ Wv,
    const float* __restrict__ W0, const float* __restrict__ W1,
    const float* __restrict__ W2, const float* __restrict__ x,
    const float* __restrict__ bq, const float* __restrict__ bk,
    const float* __restrict__ bv, u16* Wet, u16* qkvWt, u16* W0t, u16* W1t,
    u16* W2t, u16* xb, float* biasqkv) {
  const int z = blockIdx.z;
  const int tid = threadIdx.x;
  if (z >= 7) {
    if (z == 15) {
      int i = (blockIdx.y * 16 + blockIdx.x) * 256 + tid;
      if (i < 3072)
        biasqkv[i] = i < 1024 ? bq[i] : (i < 2048 ? bk[i - 1024] : bv[i - 2048]);
      return;
    }
    int blin = (z - 7) * 256 + blockIdx.y * 16 + blockIdx.x;
    int idx = (blin * 256 + tid) * 4;
    float4 f = *(const float4*)&x[idx];
    ushort4 o;
    o.x = f2bf(f.x); o.y = f2bf(f.y); o.z = f2bf(f.z); o.w = f2bf(f.w);
    *(ushort4*)&xb[idx] = o;
    return;
  }
  const float* in;
  u16* out;
  int out_rs = 1024;
  if (z == 0) { if (blockIdx.y >= 8) return; in = We; out = Wet; out_rs = 512; }
  else if (z == 1) { in = Wq; out = qkvWt; }
  else if (z == 2) { in = Wk; out = qkvWt + 1048576; }
  else if (z == 3) { in = Wv; out = qkvWt + 2097152; }
  else if (z == 4) { in = W0; out = W0t; }
  else if (z == 5) { in = W1; out = W1t; }
  else { in = W2; out = W2t; }
  __shared__ alignas(16) u16 T[64][TSP];
  const int r0 = blockIdx.y * 64, c0 = blockIdx.x * 64;
#pragma unroll
  for (int it = 0; it < 4; ++it) {
    int vi = it * 256 + tid;
    int i = vi >> 4, j4 = (vi & 15) * 4;
    float4 f = *(const float4*)&in[(size_t)(r0 + i) * 1024 + c0 + j4];
    T[i][j4 + 0] = f2bf(f.x);
    T[i][j4 + 1] = f2bf(f.y);
    T[i][j4 + 2] = f2bf(f.z);
    T[i][j4 + 3] = f2bf(f.w);
  }
  __syncthreads();
#pragma unroll
  for (int it = 0; it < 2; ++it) {
    int vi = it * 256 + tid;
    int i = vi >> 3, j8 = (vi & 7) * 8;
    bf16x8 v;
#pragma unroll
    for (int u = 0; u < 8; ++u) ((u16*)&v)[u] = T[j8 + u][i];
    *(bf16x8*)&out[(size_t)(c0 + i) * out_rs + r0 + j8] = v;
  }
}

// ---------------------------------------------------------------------------
// GEMM: C[M,N] = act(A @ Bt^T + bias [+res]). BK=64, 4 waves, M=4096.
// 1D grid, XCD-swizzled: blocks i=k (mod 8) share XCD k and a 512-row
// A-window (1MB, L2-resident) across all N-strips.
// <128,64>: wave 64x32, 48KB -> 3/CU (qkv, grid 1536).
// <128,32>: wave 64x16 (acc 4x1, 4 MFMA / 5 b128-reads), 40KB -> 4/CU at
//           grid 1024 — 128-row density at 64^2-level occupancy (N=1024).
// VT: fused V-transpose epilogue for the qkv GEMM — cols >= 2048 are the
// V slice; write vt[bh][d][s] (uint2 of 4 consecutive s) instead of qkv.
// Async dbuf, raw barriers, counted vmcnt, XOR swizzle.
// ---------------------------------------------------------------------------
template <int TM, int TN, bool VT = false>
__global__ __launch_bounds__(256, (TM == 128) ? 3 : 5) void gemm_mfma(
    const u16* __restrict__ A, const u16* __restrict__ Bt,
    const float* __restrict__ bias, const u16* __restrict__ res,
    void* __restrict__ Cout, int M, int N, int K, int relu, int f32out,
    u16* __restrict__ vt) {
  constexpr int MT = TM / 32;  // m-tiles per wave
  constexpr int NT = TN / 32;  // n-tiles per wave (>=1)
  constexpr int AI = TM / 32;  // A staging issues per lane
  constexpr int BI = (TN >= 64) ? TN / 32 : 1;  // B staging issues per lane
  constexpr int NTT = (NT < 1) ? 1 : NT;
  __shared__ alignas(16) u16 As[2][TM * 64];
  __shared__ alignas(16) u16 Bs[2][TN * 64];
  const int tid = threadIdx.x;
  const int wave = tid >> 6, lane = tid & 63;
  const int quad = lane >> 4, l16 = lane & 15;
  // XCD swizzle decode (M=4096 fixed): 8 XCD groups x YB y-blocks x NX strips
  const int ib = blockIdx.x;
  int by, bx;
  if constexpr (TM == 128) { by = (ib & 7) * 4 + ((ib >> 3) & 3); bx = ib >> 5; }
  else { by = (ib & 7) * 8 + ((ib >> 3) & 7); bx = ib >> 6; }
  const int m0 = by * TM, n0 = bx * TN;
  const int wm = (wave & 1) * (TM / 2), wn = (wave >> 1) * (TN / 2);

  f32x4 acc[MT][NTT];
#pragma unroll
  for (int i = 0; i < MT; ++i)
#pragma unroll
    for (int j = 0; j < NTT; ++j) acc[i][j] = (f32x4){0.f, 0.f, 0.f, 0.f};

  const int srow = lane >> 3;                   // 0..7
  const int schunk = (lane & 7) ^ (srow & 7);   // XOR swizzle on global side
  const u16* Ag = A + (size_t)(m0 + wave * (TM / 4) + srow) * K + schunk * 8;
  const u16* Bg = Bt + (size_t)(n0 + wave * (TN / 4) + srow) * K + schunk * 8;
  u16* AsW0 = &As[0][wave * (TM / 4) * 64];
  u16* BsW0 = &Bs[0][wave * (TN / 4) * 64];
  u16* AsW1 = &As[1][wave * (TM / 4) * 64];
  u16* BsW1 = &Bs[1][wave * (TN / 4) * 64];

#define GEMM_ISSUE(ab, bb, k)                                     \
  {                                                               \
    _Pragma("unroll") for (int i = 0; i < AI; ++i)                \
        async_cp16(Ag + (k) + (size_t)i * 8 * K, (ab) + i * 512); \
    _Pragma("unroll") for (int i = 0; i < BI; ++i)                \
        async_cp16(Bg + (k) + (size_t)i * 8 * K, (bb) + i * 512); \
  }

  GEMM_ISSUE(AsW0, BsW0, 0);
  const int T = K >> 6;
  const int swz = (l16 & 7);
  for (int t = 0; t < T; ++t) {
    const int cb = t & 1;
    S_BARRIER();  // prior compute on buf cb^1 finished everywhere
    const int kn = (t + 1 < T) ? ((t + 1) << 6) : 0;  // wrap: harmless refetch
    if (cb == 0) GEMM_ISSUE(AsW1, BsW1, kn) else GEMM_ISSUE(AsW0, BsW0, kn);
    if constexpr (AI + BI == 6)
      asm volatile("s_waitcnt vmcnt(6)" ::: "memory");  // tile-t loads landed
    else if constexpr (AI + BI == 5)
      asm volatile("s_waitcnt vmcnt(5)" ::: "memory");
    else
      asm volatile("s_waitcnt vmcnt(4)" ::: "memory");
    S_BARRIER();
#pragma unroll
    for (int kk = 0; kk < 2; ++kk) {
      bf16x8 af[MT], bfr[NTT];
#pragma unroll
      for (int mt = 0; mt < MT; ++mt)
        af[mt] = *(const bf16x8*)&As[cb][(wm + mt * 16 + l16) * 64 +
                                        ((kk * 4 + quad) ^ swz) * 8];
#pragma unroll
      for (int nt = 0; nt < NTT; ++nt)
        bfr[nt] = *(const bf16x8*)&Bs[cb][(wn + nt * 16 + l16) * 64 +
                                          ((kk * 4 + quad) ^ swz) * 8];
#pragma unroll
      for (int mt = 0; mt < MT; ++mt)
#pragma unroll
        for (int nt = 0; nt < NTT; ++nt)
          acc[mt][nt] = mfma16(af[mt], bfr[nt], acc[mt][nt]);
    }
  }
  asm volatile("s_waitcnt vmcnt(0)" ::: "memory");  // drain before LDS dealloc

#pragma unroll
  for (int nt = 0; nt < NTT; ++nt) {
    int col = n0 + wn + nt * 16 + l16;
    float bv = bias ? bias[col] : 0.f;
#pragma unroll
    for (int mt = 0; mt < MT; ++mt) {
      int row0 = m0 + wm + mt * 16 + quad * 4;
      float vv[4];
#pragma unroll
      for (int r = 0; r < 4; ++r) {
        float v = acc[mt][nt][r] + bv;
        if (res) v += bf2f(res[(size_t)(row0 + r) * N + col]);
        if (relu) v = fmaxf(v, 0.f);
        vv[r] = v;
      }
      if (VT && col >= 2048) {
        // V slice -> vt[((b*16+h)*64+d)*2048 + s], 4 consecutive s per thread
        int bb = row0 >> 11, ss = row0 & 2047;
        int hh = (col >> 6) & 15, dd = col & 63;
        uint2 pk;
        pk.x = pk2(vv[0], vv[1]);
        pk.y = pk2(vv[2], vv[3]);
        *(uint2*)&vt[(((size_t)(bb * 16 + hh) * 64 + dd) << 11) + ss] = pk;
      } else {
#pragma unroll
        for (int r = 0; r < 4; ++r) {
          if (f32out)
            ((float*)Cout)[(size_t)(row0 + r) * N + col] = vv[r];
          else
            ((u16*)Cout)[(size_t)(row0 + r) * N + col] = f2bf(vv[r]);
        }
      }
    }
  }
}

// ---------------------------------------------------------------------------
// Flash attention, transposed: S^T = K@Q^T, ctx^T = V^T@P^T. Fixed-base
// softmax (Q pre-scaled 1/8 — exact bf16 exponent shift); l via ones-MFMA on
// the bf16 P (self-consistent with truncation pack). Block = 128 q-rows x
// (b,h); wave = 32 q-rows. Grid 512, XCD-swizzled: bh = ib&31.
// Ps: stride 64 + XOR swizzle (chunk ^ (row&7)) -> <=2-way banks.
// Measured plateau of this family: 52.0-52.4 us (r3/r8); keep exact form.
// ---------------------------------------------------------------------------
__global__ __launch_bounds__(256, 2) void attn_kernel(
    const u16* __restrict__ QKV, const u16* __restrict__ Vt,
    u16* __restrict__ O) {
  __shared__ alignas(16) u16 Ks[2][64 * 64];  // [key][d], swizzled
  __shared__ alignas(16) u16 Vs[2][64 * 64];  // [d][s], swizzled
  __shared__ alignas(16) u16 Ps[4][32 * 64];  // per-wave P[qrow][key], XOR swz
  const int tid = threadIdx.x;
  const int wave = tid >> 6, lane = tid & 63;
  const int quad = lane >> 4, l16 = lane & 15;
  const int ib = blockIdx.x;
  const int bh = ib & 31, b = bh >> 4, h = bh & 15;
  const int q0 = (ib >> 5) * 128 + wave * 32;

  // Q as B-frags (k=d=quad*8+j, n=qrow=l16), pre-scaled by 1/8 (exact)
  bf16x8 qf[2][2];
#pragma unroll
  for (int qt = 0; qt < 2; ++qt) {
    const size_t qoff = (size_t)(b * 2048 + q0 + qt * 16 + l16) * 3072 + h * 64;
#pragma unroll
    for (int kk = 0; kk < 2; ++kk) {
      bf16x8 raw = *(const bf16x8*)&QKV[qoff + kk * 32 + quad * 8];
#pragma unroll
      for (int u = 0; u < 8; ++u)
        ((u16*)&raw)[u] = f2bf(0.125f * bf2f(((u16*)&raw)[u]));
      qf[qt][kk] = raw;
    }
  }
  bf16x8 ones;
#pragma unroll
  for (int u = 0; u < 8; ++u) ((u16*)&ones)[u] = 0x3F80;  // 1.0bf

  f32x4 o[4][2];  // ctx^T [d-tile][q-tile]
  f32x4 l_acc[2] = {(f32x4){0.f, 0.f, 0.f, 0.f}, (f32x4){0.f, 0.f, 0.f, 0.f}};
#pragma unroll
  for (int mt = 0; mt < 4; ++mt)
#pragma unroll
    for (int qt = 0; qt < 2; ++qt) o[mt][qt] = (f32x4){0.f, 0.f, 0.f, 0.f};

  const int srow = lane >> 3;
  const int schunk = (lane & 7) ^ (srow & 7);
  const u16* Kg = QKV + (size_t)(b * 2048 + wave * 16 + srow) * 3072 + 1024 +
                  h * 64 + schunk * 8;
  const u16* Vg = Vt + (size_t)((b * 16 + h) * 64 + wave * 16 + srow) * 2048 +
                  schunk * 8;
  u16* KsW0 = &Ks[0][(wave * 16) * 64];
  u16* VsW0 = &Vs[0][(wave * 16) * 64];
  u16* KsW1 = &Ks[1][(wave * 16) * 64];
  u16* VsW1 = &Vs[1][(wave * 16) * 64];

#define ATTN_ISSUE(kb, vb, kt)                                \
  {                                                           \
    async_cp16(Kg + (size_t)(kt) * 3072, (kb));               \
    async_cp16(Kg + (size_t)((kt) + 8) * 3072, (kb) + 512);   \
    async_cp16(Vg + (kt), (vb));                              \
    async_cp16(Vg + (kt) + (size_t)8 * 2048, (vb) + 512);     \
  }

  ATTN_ISSUE(KsW0, VsW0, 0);
  const int swz = (l16 & 7);
  u16* PsW = &Ps[wave][0];
  for (int t = 0; t < 32; ++t) {
    const int cb = t & 1;
    S_BARRIER();
    const int ktn = (t + 1 < 32) ? ((t + 1) * 64) : 0;
    if (cb == 0) ATTN_ISSUE(KsW1, VsW1, ktn) else ATTN_ISSUE(KsW0, VsW0, ktn);
    asm volatile("s_waitcnt vmcnt(4)" ::: "memory");
    S_BARRIER();

    // S^T = K @ Q^T : D[m=key][n=qrow]
    f32x4 st[4][2];
#pragma unroll
    for (int km = 0; km < 4; ++km)
#pragma unroll
      for (int qt = 0; qt < 2; ++qt) st[km][qt] = (f32x4){0.f, 0.f, 0.f, 0.f};
    __builtin_amdgcn_s_setprio(1);
#pragma unroll
    for (int kk = 0; kk < 2; ++kk)
#pragma unroll
      for (int km = 0; km < 4; ++km) {
        bf16x8 kf = *(const bf16x8*)&Ks[cb][(km * 16 + l16) * 64 +
                                           ((kk * 4 + quad) ^ swz) * 8];
        st[km][0] = mfma16(kf, qf[0][kk], st[km][0]);
        st[km][1] = mfma16(kf, qf[1][kk], st[km][1]);
      }
    __builtin_amdgcn_s_setprio(0);

    // exp + truncating v_perm pack -> one b64 write per (qt,km), XOR-swizzled
#pragma unroll
    for (int qt = 0; qt < 2; ++qt)
#pragma unroll
      for (int km = 0; km < 4; ++km) {
        float e0 = __expf(st[km][qt][0]), e1 = __expf(st[km][qt][1]);
        float e2 = __expf(st[km][qt][2]), e3 = __expf(st[km][qt][3]);
        uint2 pk;
        pk.x = pk2t(e0, e1);
        pk.y = pk2t(e2, e3);
        // row = qt*16+l16; 16B chunk = km*2+(quad>>1), swizzled by l16&7
        *(uint2*)&PsW[(qt * 16 + l16) * 64 +
                      ((km * 2 + (quad >> 1)) ^ swz) * 8 + (quad & 1) * 4] = pk;
      }
    asm volatile("s_waitcnt lgkmcnt(0)" ::: "memory");  // wave-local round-trip

    // ctx^T += V^T @ P^T ; l += ones @ P^T (row sums of bf16 P)
    __builtin_amdgcn_s_setprio(1);
#pragma unroll
    for (int kk2 = 0; kk2 < 2; ++kk2) {
      bf16x8 pf0 =
          *(const bf16x8*)&PsW[l16 * 64 + ((kk2 * 4 + quad) ^ swz) * 8];
      bf16x8 pf1 = *(const bf16x8*)&PsW[(16 + l16) * 64 +
                                        ((kk2 * 4 + quad) ^ swz) * 8];
      l_acc[0] = mfma16(ones, pf0, l_acc[0]);
      l_acc[1] = mfma16(ones, pf1, l_acc[1]);
#pragma unroll
      for (int mt = 0; mt < 4; ++mt) {
        bf16x8 vf = *(const bf16x8*)&Vs[cb][(mt * 16 + l16) * 64 +
                                           ((kk2 * 4 + quad) ^ swz) * 8];
        o[mt][0] = mfma16(vf, pf0, o[mt][0]);
        o[mt][1] = mfma16(vf, pf1, o[mt][1]);
      }
    }
    __builtin_amdgcn_s_setprio(0);
  }
  asm volatile("s_waitcnt vmcnt(0)" ::: "memory");  // drain before LDS dealloc

  // epilogue: lane holds ctx^T[d=mt*16+quad*4+r][qrow=qt*16+l16]; l_acc rows
  // are all identical (= sum over keys for qrow=l16) -> no shuffles needed
#pragma unroll
  for (int qt = 0; qt < 2; ++qt) {
    float inv = 1.f / l_acc[qt][0];
    size_t base = (size_t)(b * 2048 + q0 + qt * 16 + l16) * 1024 + h * 64;
#pragma unroll
    for (int mt = 0; mt < 4; ++mt) {
      uint2 pk;
      pk.x = pk2(o[mt][qt][0] * inv, o[mt][qt][1] * inv);
      pk.y = pk2(o[mt][qt][2] * inv, o[mt][qt][3] * inv);
      *(uint2*)&O[base + mt * 16 + quad * 4] = pk;
    }
  }
}

// ---------------------------------------------------------------------------
extern "C" void kernel_launch(void* const* d_in, const int* in_sizes, int n_in,
                              void* d_out, int out_size, void* d_ws,
                              size_t ws_size, hipStream_t stream) {
  const float* x = (const float*)d_in[0];
  const float* We = (const float*)d_in[1];
  const float* be = (const float*)d_in[2];
  const float* Wq = (const float*)d_in[3];
  const float* bq = (const float*)d_in[4];
  const float* Wk = (const float*)d_in[5];
  const float* bk = (const float*)d_in[6];
  const float* Wv = (const float*)d_in[7];
  const float* bv = (const float*)d_in[8];
  const float* W0 = (const float*)d_in[9];
  const float* b0 = (const float*)d_in[10];
  const float* W1 = (const float*)d_in[11];
  const float* b1 = (const float*)d_in[12];
  const float* W2 = (const float*)d_in[13];
  const float* b2 = (const float*)d_in[14];

  u16* ws = (u16*)d_ws;
  u16* xb = ws;                         // 2,097,152
  u16* Wet = xb + 2097152;              //   524,288
  u16* qkvWt = Wet + 524288;            // 3,145,728
  u16* ctx = ws;                        // alias after attn input no longer needed
  u16* W0t = qkvWt + 3145728;
  u16* W1t = W0t + 1048576;
  u16* W2t = W1t + 1048576;
  float* biasqkv = (float*)(W2t + 1048576);  // 3072 f32
  u16* e = W2t + 1048576 + 6144;        // 4,194,304
  u16* qkv = e + 4194304;               // 12,582,912
  u16* vtb = qkv + 12582912;            // 4,194,304
  u16* mha = qkv;                       // alias: qkv dead after attn
  u16* h1 = e;                          // alias: e dead after W0-gemm

  prep_fused<<<dim3(16, 16, 16), 256, 0, stream>>>(
      We, Wq, Wk, Wv, W0, W1, W2, x, bq, bk, bv, Wet, qkvWt, W0t, W1t, W2t,
      xb, biasqkv);

  // e = x @ We + be   (<128,32>: grid 1024 = 32 m-blocks x 32 n-strips, 4/CU)
  gemm_mfma<128, 32><<<1024, 256, 0, stream>>>(xb, Wet, be, nullptr, e, 4096,
                                               1024, 512, 0, 0, nullptr);
  // qkv = e @ [Wq|Wk|Wv] + [bq|bk|bv]; V-slice transposed into vtb in-epilogue
  gemm_mfma<128, 64, true><<<1536, 256, 0, stream>>>(
      e, qkvWt, biasqkv, nullptr, qkv, 4096, 3072, 1024, 0, 0, vtb);
  attn_kernel<<<512, 256, 0, stream>>>(qkv, vtb, ctx);
  // mha = e + ctx @ W0 + b0
  gemm_mfma<128, 32><<<1024, 256, 0, stream>>>(ctx, W0t, b0, e, mha, 4096,
                                               1024, 1024, 0, 0, nullptr);
  // h1 = relu(mha @ W1 + b1)
  gemm_mfma<128, 32><<<1024, 256, 0, stream>>>(mha, W1t, b1, nullptr, h1, 4096,
                                               1024, 1024, 1, 0, nullptr);
  // out = mha + h1 @ W2 + b2 (f32)
  gemm_mfma<128, 32><<<1024, 256, 0, stream>>>(h1, W2t, b2, mha, d_out, 4096,
                                               1024, 1024, 0, 1, nullptr);
}

// Round 14
// 247.490 us; speedup vs baseline: 1.0618x; 1.0618x over previous
//
#include <hip/hip_runtime.h>

typedef unsigned short u16;
typedef __bf16 bf16x8 __attribute__((ext_vector_type(8)));
typedef float f32x4 __attribute__((ext_vector_type(4)));

__device__ __forceinline__ float bf2f(u16 u) {
  return __builtin_bit_cast(float, (unsigned)u << 16);
}
__device__ __forceinline__ u16 f2bf(float f) {
  unsigned u = __builtin_bit_cast(unsigned, f);
  u += 0x7FFFu + ((u >> 16) & 1u);  // RNE
  return (u16)(u >> 16);
}
__device__ __forceinline__ unsigned pk2(float a, float b) {
  return (unsigned)f2bf(a) | ((unsigned)f2bf(b) << 16);
}
// truncating pack: [b.hi16 | a.hi16] in ONE v_perm_b32 (bias cancels in P/l)
__device__ __forceinline__ unsigned pk2t(float a, float b) {
  return __builtin_amdgcn_perm(__builtin_bit_cast(unsigned, b),
                               __builtin_bit_cast(unsigned, a), 0x07060302u);
}
__device__ __forceinline__ f32x4 mfma16(bf16x8 a, bf16x8 b, f32x4 c) {
  return __builtin_amdgcn_mfma_f32_16x16x32_bf16(a, b, c, 0, 0, 0);
}
// async 16B/lane global->LDS; LDS dest = wave-uniform base + lane*16
__device__ __forceinline__ void async_cp16(const u16* g, u16* l) {
  __builtin_amdgcn_global_load_lds((const __attribute__((address_space(1))) void*)g,
                                   (__attribute__((address_space(3))) void*)l, 16, 0, 0);
}
#define S_BARRIER() asm volatile("s_barrier" ::: "memory")

// ---------------------------------------------------------------------------
// Fused preprocessing, grid (16,16,16):
//   z 0..6  : weight transposes [R][1024] f32 -> [1024][R] bf16
//   z 7..14 : cast x f32 -> bf16 (2M elements)
//   z 15    : bias concat (first 12 blocks)
// ---------------------------------------------------------------------------
#define TSP 72
__global__ __launch_bounds__(256) void prep_fused(
    const float* __restrict__ We, const float* __restrict__ Wq,
    const float* __restrict__ Wk, const float* __restrict__ Wv,
    const float* __restrict__ W0, const float* __restrict__ W1,
    const float* __restrict__ W2, const float* __restrict__ x,
    const float* __restrict__ bq, const float* __restrict__ bk,
    const float* __restrict__ bv, u16* Wet, u16* qkvWt, u16* W0t, u16* W1t,
    u16* W2t, u16* xb, float* biasqkv) {
  const int z = blockIdx.z;
  const int tid = threadIdx.x;
  if (z >= 7) {
    if (z == 15) {
      int i = (blockIdx.y * 16 + blockIdx.x) * 256 + tid;
      if (i < 3072)
        biasqkv[i] = i < 1024 ? bq[i] : (i < 2048 ? bk[i - 1024] : bv[i - 2048]);
      return;
    }
    int blin = (z - 7) * 256 + blockIdx.y * 16 + blockIdx.x;
    int idx = (blin * 256 + tid) * 4;
    float4 f = *(const float4*)&x[idx];
    ushort4 o;
    o.x = f2bf(f.x); o.y = f2bf(f.y); o.z = f2bf(f.z); o.w = f2bf(f.w);
    *(ushort4*)&xb[idx] = o;
    return;
  }
  const float* in;
  u16* out;
  int out_rs = 1024;
  if (z == 0) { if (blockIdx.y >= 8) return; in = We; out = Wet; out_rs = 512; }
  else if (z == 1) { in = Wq; out = qkvWt; }
  else if (z == 2) { in = Wk; out = qkvWt + 1048576; }
  else if (z == 3) { in = Wv; out = qkvWt + 2097152; }
  else if (z == 4) { in = W0; out = W0t; }
  else if (z == 5) { in = W1; out = W1t; }
  else { in = W2; out = W2t; }
  __shared__ alignas(16) u16 T[64][TSP];
  const int r0 = blockIdx.y * 64, c0 = blockIdx.x * 64;
#pragma unroll
  for (int it = 0; it < 4; ++it) {
    int vi = it * 256 + tid;
    int i = vi >> 4, j4 = (vi & 15) * 4;
    float4 f = *(const float4*)&in[(size_t)(r0 + i) * 1024 + c0 + j4];
    T[i][j4 + 0] = f2bf(f.x);
    T[i][j4 + 1] = f2bf(f.y);
    T[i][j4 + 2] = f2bf(f.z);
    T[i][j4 + 3] = f2bf(f.w);
  }
  __syncthreads();
#pragma unroll
  for (int it = 0; it < 2; ++it) {
    int vi = it * 256 + tid;
    int i = vi >> 3, j8 = (vi & 7) * 8;
    bf16x8 v;
#pragma unroll
    for (int u = 0; u < 8; ++u) ((u16*)&v)[u] = T[j8 + u][i];
    *(bf16x8*)&out[(size_t)(c0 + i) * out_rs + r0 + j8] = v;
  }
}

// ---------------------------------------------------------------------------
// GEMM: C[M,N] = act(A @ Bt^T + bias [+res]). BK=64, 4 waves, M=4096.
// 1D grid, XCD-swizzled: blocks i=k (mod 8) share XCD k and a 512-row
// A-window (1MB, L2-resident) across all N-strips.
// <128,64>: wave 64x32, 48KB -> 3/CU (qkv, grid 1536).
// <64,64>:  wave 32x32, 32KB -> 4-5/CU at grid 1024 — measured best for the
//           N=1024 strips (beats <128,128>, <128,64>@512, <128,32> — r3/r13).
// VT: fused V-transpose epilogue for the qkv GEMM — cols >= 2048 are the
// V slice; write vt[bh][d][s] (uint2 of 4 consecutive s) instead of qkv.
// Async dbuf, raw barriers, counted vmcnt, XOR swizzle.
// ---------------------------------------------------------------------------
template <int TM, int TN, bool VT = false>
__global__ __launch_bounds__(256, (TM == 128) ? 3 : 5) void gemm_mfma(
    const u16* __restrict__ A, const u16* __restrict__ Bt,
    const float* __restrict__ bias, const u16* __restrict__ res,
    void* __restrict__ Cout, int M, int N, int K, int relu, int f32out,
    u16* __restrict__ vt) {
  constexpr int MT = TM / 32;  // m-tiles per wave
  constexpr int NT = TN / 32;  // n-tiles per wave
  constexpr int AI = TM / 32;  // A staging issues per lane
  constexpr int BI = TN / 32;  // B staging issues per lane
  __shared__ alignas(16) u16 As[2][TM * 64];
  __shared__ alignas(16) u16 Bs[2][TN * 64];
  const int tid = threadIdx.x;
  const int wave = tid >> 6, lane = tid & 63;
  const int quad = lane >> 4, l16 = lane & 15;
  // XCD swizzle decode (M=4096 fixed): 8 XCD groups x YB y-blocks x NX strips
  const int ib = blockIdx.x;
  int by, bx;
  if constexpr (TM == 128) { by = (ib & 7) * 4 + ((ib >> 3) & 3); bx = ib >> 5; }
  else { by = (ib & 7) * 8 + ((ib >> 3) & 7); bx = ib >> 6; }
  const int m0 = by * TM, n0 = bx * TN;
  const int wm = (wave & 1) * (TM / 2), wn = (wave >> 1) * (TN / 2);

  f32x4 acc[MT][NT];
#pragma unroll
  for (int i = 0; i < MT; ++i)
#pragma unroll
    for (int j = 0; j < NT; ++j) acc[i][j] = (f32x4){0.f, 0.f, 0.f, 0.f};

  const int srow = lane >> 3;                   // 0..7
  const int schunk = (lane & 7) ^ (srow & 7);   // XOR swizzle on global side
  const u16* Ag = A + (size_t)(m0 + wave * (TM / 4) + srow) * K + schunk * 8;
  const u16* Bg = Bt + (size_t)(n0 + wave * (TN / 4) + srow) * K + schunk * 8;
  u16* AsW0 = &As[0][wave * (TM / 4) * 64];
  u16* BsW0 = &Bs[0][wave * (TN / 4) * 64];
  u16* AsW1 = &As[1][wave * (TM / 4) * 64];
  u16* BsW1 = &Bs[1][wave * (TN / 4) * 64];

#define GEMM_ISSUE(ab, bb, k)                                     \
  {                                                               \
    _Pragma("unroll") for (int i = 0; i < AI; ++i)                \
        async_cp16(Ag + (k) + (size_t)i * 8 * K, (ab) + i * 512); \
    _Pragma("unroll") for (int i = 0; i < BI; ++i)                \
        async_cp16(Bg + (k) + (size_t)i * 8 * K, (bb) + i * 512); \
  }

  GEMM_ISSUE(AsW0, BsW0, 0);
  const int T = K >> 6;
  const int swz = (l16 & 7);
  for (int t = 0; t < T; ++t) {
    const int cb = t & 1;
    S_BARRIER();  // prior compute on buf cb^1 finished everywhere
    const int kn = (t + 1 < T) ? ((t + 1) << 6) : 0;  // wrap: harmless refetch
    if (cb == 0) GEMM_ISSUE(AsW1, BsW1, kn) else GEMM_ISSUE(AsW0, BsW0, kn);
    if constexpr (AI + BI == 6)
      asm volatile("s_waitcnt vmcnt(6)" ::: "memory");  // tile-t loads landed
    else
      asm volatile("s_waitcnt vmcnt(4)" ::: "memory");
    S_BARRIER();
#pragma unroll
    for (int kk = 0; kk < 2; ++kk) {
      bf16x8 af[MT], bfr[NT];
#pragma unroll
      for (int mt = 0; mt < MT; ++mt)
        af[mt] = *(const bf16x8*)&As[cb][(wm + mt * 16 + l16) * 64 +
                                        ((kk * 4 + quad) ^ swz) * 8];
#pragma unroll
      for (int nt = 0; nt < NT; ++nt)
        bfr[nt] = *(const bf16x8*)&Bs[cb][(wn + nt * 16 + l16) * 64 +
                                          ((kk * 4 + quad) ^ swz) * 8];
#pragma unroll
      for (int mt = 0; mt < MT; ++mt)
#pragma unroll
        for (int nt = 0; nt < NT; ++nt)
          acc[mt][nt] = mfma16(af[mt], bfr[nt], acc[mt][nt]);
    }
  }
  asm volatile("s_waitcnt vmcnt(0)" ::: "memory");  // drain before LDS dealloc

#pragma unroll
  for (int nt = 0; nt < NT; ++nt) {
    int col = n0 + wn + nt * 16 + l16;
    float bv = bias ? bias[col] : 0.f;
#pragma unroll
    for (int mt = 0; mt < MT; ++mt) {
      int row0 = m0 + wm + mt * 16 + quad * 4;
      float vv[4];
#pragma unroll
      for (int r = 0; r < 4; ++r) {
        float v = acc[mt][nt][r] + bv;
        if (res) v += bf2f(res[(size_t)(row0 + r) * N + col]);
        if (relu) v = fmaxf(v, 0.f);
        vv[r] = v;
      }
      if (VT && col >= 2048) {
        // V slice -> vt[((b*16+h)*64+d)*2048 + s], 4 consecutive s per thread
        int bb = row0 >> 11, ss = row0 & 2047;
        int hh = (col >> 6) & 15, dd = col & 63;
        uint2 pk;
        pk.x = pk2(vv[0], vv[1]);
        pk.y = pk2(vv[2], vv[3]);
        *(uint2*)&vt[(((size_t)(bb * 16 + hh) * 64 + dd) << 11) + ss] = pk;
      } else {
#pragma unroll
        for (int r = 0; r < 4; ++r) {
          if (f32out)
            ((float*)Cout)[(size_t)(row0 + r) * N + col] = vv[r];
          else
            ((u16*)Cout)[(size_t)(row0 + r) * N + col] = f2bf(vv[r]);
        }
      }
    }
  }
}

// ---------------------------------------------------------------------------
// Flash attention, transposed: S^T = K@Q^T, ctx^T = V^T@P^T. Fixed-base
// softmax (Q pre-scaled 1/8 — exact bf16 exponent shift); l via ones-MFMA on
// the bf16 P (self-consistent with truncation pack). Block = 128 q-rows x
// (b,h); wave = 32 q-rows. Grid 512, XCD-swizzled: bh = ib&31.
// Ps: stride 64 + XOR swizzle (chunk ^ (row&7)) -> <=2-way banks.
// Measured plateau of this family: 52.0-52.4 us (r3/r8); keep exact form.
// ---------------------------------------------------------------------------
__global__ __launch_bounds__(256, 2) void attn_kernel(
    const u16* __restrict__ QKV, const u16* __restrict__ Vt,
    u16* __restrict__ O) {
  __shared__ alignas(16) u16 Ks[2][64 * 64];  // [key][d], swizzled
  __shared__ alignas(16) u16 Vs[2][64 * 64];  // [d][s], swizzled
  __shared__ alignas(16) u16 Ps[4][32 * 64];  // per-wave P[qrow][key], XOR swz
  const int tid = threadIdx.x;
  const int wave = tid >> 6, lane = tid & 63;
  const int quad = lane >> 4, l16 = lane & 15;
  const int ib = blockIdx.x;
  const int bh = ib & 31, b = bh >> 4, h = bh & 15;
  const int q0 = (ib >> 5) * 128 + wave * 32;

  // Q as B-frags (k=d=quad*8+j, n=qrow=l16), pre-scaled by 1/8 (exact)
  bf16x8 qf[2][2];
#pragma unroll
  for (int qt = 0; qt < 2; ++qt) {
    const size_t qoff = (size_t)(b * 2048 + q0 + qt * 16 + l16) * 3072 + h * 64;
#pragma unroll
    for (int kk = 0; kk < 2; ++kk) {
      bf16x8 raw = *(const bf16x8*)&QKV[qoff + kk * 32 + quad * 8];
#pragma unroll
      for (int u = 0; u < 8; ++u)
        ((u16*)&raw)[u] = f2bf(0.125f * bf2f(((u16*)&raw)[u]));
      qf[qt][kk] = raw;
    }
  }
  bf16x8 ones;
#pragma unroll
  for (int u = 0; u < 8; ++u) ((u16*)&ones)[u] = 0x3F80;  // 1.0bf

  f32x4 o[4][2];  // ctx^T [d-tile][q-tile]
  f32x4 l_acc[2] = {(f32x4){0.f, 0.f, 0.f, 0.f}, (f32x4){0.f, 0.f, 0.f, 0.f}};
#pragma unroll
  for (int mt = 0; mt < 4; ++mt)
#pragma unroll
    for (int qt = 0; qt < 2; ++qt) o[mt][qt] = (f32x4){0.f, 0.f, 0.f, 0.f};

  const int srow = lane >> 3;
  const int schunk = (lane & 7) ^ (srow & 7);
  const u16* Kg = QKV + (size_t)(b * 2048 + wave * 16 + srow) * 3072 + 1024 +
                  h * 64 + schunk * 8;
  const u16* Vg = Vt + (size_t)((b * 16 + h) * 64 + wave * 16 + srow) * 2048 +
                  schunk * 8;
  u16* KsW0 = &Ks[0][(wave * 16) * 64];
  u16* VsW0 = &Vs[0][(wave * 16) * 64];
  u16* KsW1 = &Ks[1][(wave * 16) * 64];
  u16* VsW1 = &Vs[1][(wave * 16) * 64];

#define ATTN_ISSUE(kb, vb, kt)                                \
  {                                                           \
    async_cp16(Kg + (size_t)(kt) * 3072, (kb));               \
    async_cp16(Kg + (size_t)((kt) + 8) * 3072, (kb) + 512);   \
    async_cp16(Vg + (kt), (vb));                              \
    async_cp16(Vg + (kt) + (size_t)8 * 2048, (vb) + 512);     \
  }

  ATTN_ISSUE(KsW0, VsW0, 0);
  const int swz = (l16 & 7);
  u16* PsW = &Ps[wave][0];
  for (int t = 0; t < 32; ++t) {
    const int cb = t & 1;
    S_BARRIER();
    const int ktn = (t + 1 < 32) ? ((t + 1) * 64) : 0;
    if (cb == 0) ATTN_ISSUE(KsW1, VsW1, ktn) else ATTN_ISSUE(KsW0, VsW0, ktn);
    asm volatile("s_waitcnt vmcnt(4)" ::: "memory");
    S_BARRIER();

    // S^T = K @ Q^T : D[m=key][n=qrow]
    f32x4 st[4][2];
#pragma unroll
    for (int km = 0; km < 4; ++km)
#pragma unroll
      for (int qt = 0; qt < 2; ++qt) st[km][qt] = (f32x4){0.f, 0.f, 0.f, 0.f};
    __builtin_amdgcn_s_setprio(1);
#pragma unroll
    for (int kk = 0; kk < 2; ++kk)
#pragma unroll
      for (int km = 0; km < 4; ++km) {
        bf16x8 kf = *(const bf16x8*)&Ks[cb][(km * 16 + l16) * 64 +
                                           ((kk * 4 + quad) ^ swz) * 8];
        st[km][0] = mfma16(kf, qf[0][kk], st[km][0]);
        st[km][1] = mfma16(kf, qf[1][kk], st[km][1]);
      }
    __builtin_amdgcn_s_setprio(0);

    // exp + truncating v_perm pack -> one b64 write per (qt,km), XOR-swizzled
#pragma unroll
    for (int qt = 0; qt < 2; ++qt)
#pragma unroll
      for (int km = 0; km < 4; ++km) {
        float e0 = __expf(st[km][qt][0]), e1 = __expf(st[km][qt][1]);
        float e2 = __expf(st[km][qt][2]), e3 = __expf(st[km][qt][3]);
        uint2 pk;
        pk.x = pk2t(e0, e1);
        pk.y = pk2t(e2, e3);
        // row = qt*16+l16; 16B chunk = km*2+(quad>>1), swizzled by l16&7
        *(uint2*)&PsW[(qt * 16 + l16) * 64 +
                      ((km * 2 + (quad >> 1)) ^ swz) * 8 + (quad & 1) * 4] = pk;
      }
    asm volatile("s_waitcnt lgkmcnt(0)" ::: "memory");  // wave-local round-trip

    // ctx^T += V^T @ P^T ; l += ones @ P^T (row sums of bf16 P)
    __builtin_amdgcn_s_setprio(1);
#pragma unroll
    for (int kk2 = 0; kk2 < 2; ++kk2) {
      bf16x8 pf0 =
          *(const bf16x8*)&PsW[l16 * 64 + ((kk2 * 4 + quad) ^ swz) * 8];
      bf16x8 pf1 = *(const bf16x8*)&PsW[(16 + l16) * 64 +
                                        ((kk2 * 4 + quad) ^ swz) * 8];
      l_acc[0] = mfma16(ones, pf0, l_acc[0]);
      l_acc[1] = mfma16(ones, pf1, l_acc[1]);
#pragma unroll
      for (int mt = 0; mt < 4; ++mt) {
        bf16x8 vf = *(const bf16x8*)&Vs[cb][(mt * 16 + l16) * 64 +
                                           ((kk2 * 4 + quad) ^ swz) * 8];
        o[mt][0] = mfma16(vf, pf0, o[mt][0]);
        o[mt][1] = mfma16(vf, pf1, o[mt][1]);
      }
    }
    __builtin_amdgcn_s_setprio(0);
  }
  asm volatile("s_waitcnt vmcnt(0)" ::: "memory");  // drain before LDS dealloc

  // epilogue: lane holds ctx^T[d=mt*16+quad*4+r][qrow=qt*16+l16]; l_acc rows
  // are all identical (= sum over keys for qrow=l16) -> no shuffles needed
#pragma unroll
  for (int qt = 0; qt < 2; ++qt) {
    float inv = 1.f / l_acc[qt][0];
    size_t base = (size_t)(b * 2048 + q0 + qt * 16 + l16) * 1024 + h * 64;
#pragma unroll
    for (int mt = 0; mt < 4; ++mt) {
      uint2 pk;
      pk.x = pk2(o[mt][qt][0] * inv, o[mt][qt][1] * inv);
      pk.y = pk2(o[mt][qt][2] * inv, o[mt][qt][3] * inv);
      *(uint2*)&O[base + mt * 16 + quad * 4] = pk;
    }
  }
}

// ---------------------------------------------------------------------------
extern "C" void kernel_launch(void* const* d_in, const int* in_sizes, int n_in,
                              void* d_out, int out_size, void* d_ws,
                              size_t ws_size, hipStream_t stream) {
  const float* x = (const float*)d_in[0];
  const float* We = (const float*)d_in[1];
  const float* be = (const float*)d_in[2];
  const float* Wq = (const float*)d_in[3];
  const float* bq = (const float*)d_in[4];
  const float* Wk = (const float*)d_in[5];
  const float* bk = (const float*)d_in[6];
  const float* Wv = (const float*)d_in[7];
  const float* bv = (const float*)d_in[8];
  const float* W0 = (const float*)d_in[9];
  const float* b0 = (const float*)d_in[10];
  const float* W1 = (const float*)d_in[11];
  const float* b1 = (const float*)d_in[12];
  const float* W2 = (const float*)d_in[13];
  const float* b2 = (const float*)d_in[14];

  u16* ws = (u16*)d_ws;
  u16* xb = ws;                         // 2,097,152
  u16* Wet = xb + 2097152;              //   524,288
  u16* qkvWt = Wet + 524288;            // 3,145,728
  u16* ctx = ws;                        // alias after attn input no longer needed
  u16* W0t = qkvWt + 3145728;
  u16* W1t = W0t + 1048576;
  u16* W2t = W1t + 1048576;
  float* biasqkv = (float*)(W2t + 1048576);  // 3072 f32
  u16* e = W2t + 1048576 + 6144;        // 4,194,304
  u16* qkv = e + 4194304;               // 12,582,912
  u16* vtb = qkv + 12582912;            // 4,194,304
  u16* mha = qkv;                       // alias: qkv dead after attn
  u16* h1 = e;                          // alias: e dead after W0-gemm

  prep_fused<<<dim3(16, 16, 16), 256, 0, stream>>>(
      We, Wq, Wk, Wv, W0, W1, W2, x, bq, bk, bv, Wet, qkvWt, W0t, W1t, W2t,
      xb, biasqkv);

  // e = x @ We + be
  gemm_mfma<64, 64><<<1024, 256, 0, stream>>>(xb, Wet, be, nullptr, e, 4096,
                                              1024, 512, 0, 0, nullptr);
  // qkv = e @ [Wq|Wk|Wv] + [bq|bk|bv]; V-slice transposed into vtb in-epilogue
  gemm_mfma<128, 64, true><<<1536, 256, 0, stream>>>(
      e, qkvWt, biasqkv, nullptr, qkv, 4096, 3072, 1024, 0, 0, vtb);
  attn_kernel<<<512, 256, 0, stream>>>(qkv, vtb, ctx);
  // mha = e + ctx @ W0 + b0
  gemm_mfma<64, 64><<<1024, 256, 0, stream>>>(ctx, W0t, b0, e, mha, 4096, 1024,
                                              1024, 0, 0, nullptr);
  // h1 = relu(mha @ W1 + b1)
  gemm_mfma<64, 64><<<1024, 256, 0, stream>>>(mha, W1t, b1, nullptr, h1, 4096,
                                              1024, 1024, 1, 0, nullptr);
  // out = mha + h1 @ W2 + b2 (f32)
  gemm_mfma<64, 64><<<1024, 256, 0, stream>>>(h1, W2t, b2, mha, d_out, 4096,
                                              1024, 1024, 0, 1, nullptr);
}